// Round 1
// baseline (26155.978 us; speedup 1.0000x reference)
//
#include <hip/hip_runtime.h>

// Problem constants
#define BD   64      // batch per direction
#define DD   2048
#define HH   4096
#define NSS  25
#define BBr  128     // combined rows (fwd 0..63, bwd 64..127)

typedef _Float16 halfx8 __attribute__((ext_vector_type(8)));
typedef float    floatx4 __attribute__((ext_vector_type(4)));

__device__ __forceinline__ unsigned short f2h_bits(float x) {
    union { _Float16 h; unsigned short u; } c;
    c.h = (_Float16)x;
    return c.u;
}

// ---------------------------------------------------------------------------
// init: pos rows 0..63 and 64..127 both start from `position`; mom from
// momentum_f / momentum_b. sld zeroed (ws is poisoned 0xAA each launch).
// ---------------------------------------------------------------------------
__global__ void init_kernel(const float* __restrict__ position,
                            const float* __restrict__ momf,
                            const float* __restrict__ momb,
                            float* __restrict__ pos, float* __restrict__ mom,
                            float* __restrict__ sld) {
    int idx = blockIdx.x * 256 + threadIdx.x;   // over BBr*DD
    int r = idx >> 11, d = idx & 2047;
    pos[idx] = position[((r & 63) << 11) + d];
    mom[idx] = (r < 64) ? momf[(r << 11) + d] : momb[((r - 64) << 11) + d];
    if (idx < BBr) sld[idx] = 0.f;
}

// ---------------------------------------------------------------------------
// prep: build f16 A-operand (BBr x 2D): [a | b] per row.
// mom update: a = pos, b = sin(pos).  pos update: a = mom, b = m_param*pos.
// ---------------------------------------------------------------------------
__global__ void prep_mom_kernel(const float* __restrict__ pos,
                                unsigned short* __restrict__ Abuf) {
    int idx = blockIdx.x * 256 + threadIdx.x;
    int r = idx >> 11, d = idx & 2047;
    float p = pos[idx];
    Abuf[(r << 12) + d]        = f2h_bits(p);
    Abuf[(r << 12) + 2048 + d] = f2h_bits(sinf(p));
}

__global__ void prep_pos_kernel(const float* __restrict__ pos,
                                const float* __restrict__ mom,
                                const float* __restrict__ masks,
                                int sF, int sB, int sub,
                                unsigned short* __restrict__ Abuf) {
    int idx = blockIdx.x * 256 + threadIdx.x;
    int r = idx >> 11, d = idx & 2047;
    float m;
    if (r < 64) {
        float mf = masks[sF * 2048 + d];
        m = (sub == 2) ? mf : 1.f - mf;
    } else {
        float mb = masks[sB * 2048 + d];
        m = (sub == 2) ? 1.f - mb : mb;
    }
    Abuf[(r << 12) + d]        = f2h_bits(mom[idx]);
    Abuf[(r << 12) + 2048 + d] = f2h_bits(m * pos[idx]);
}

// ---------------------------------------------------------------------------
// Generic MFMA GEMM: C(M=128 x N) = A(f16, row-major, lda) @ Bw(fp32 K x N,
// converted to f16 on the fly). BM=32, BN=64, BK=32; 4 waves, each 16x32.
// BMODE 0: B rows from {W1 (k<2048), W2}, ldb = H.     EPI 0: relu(+b1+t@Wt) -> f16
// BMODE 1: B = Wh, ldb = H.                            EPI 1: relu(+bh)      -> f16
// BMODE 2: B cols from {Ws|Wtr|Wq} (N=3D), ldb = D.    EPI 2: raw fp32
// ---------------------------------------------------------------------------
template <int BMODE, int EPI>
__global__ __launch_bounds__(256) void gemm_kernel(
        const unsigned short* __restrict__ A, int lda, int K,
        const float* __restrict__ Bp0, const float* __restrict__ Bp1,
        const float* __restrict__ Bp2, int ldb,
        void* __restrict__ Cout, int ldc,
        const float* __restrict__ biasp, const float* __restrict__ Wtn,
        const float* __restrict__ ts, int sF, int sB) {
    __shared__ unsigned short As[32][40];   // pitch 80B: 16B-aligned rows
    __shared__ unsigned short Bs[64][40];   // transposed [n][k]

    const int tid  = threadIdx.x;
    const int wave = tid >> 6;
    const int lane = tid & 63;
    const int fl   = lane & 15;
    const int qd   = lane >> 4;
    const int bm   = blockIdx.y * 32;
    const int bn   = blockIdx.x * 64;
    const int wm   = (wave >> 1) * 16;  // 0/16
    const int wn   = (wave & 1) * 32;   // 0/32

    // A staging: thread -> 4 f16 (8B). row = tid>>3 (0..31), kchunk=(tid&7)*4
    const int ar = tid >> 3;
    const int ak = (tid & 7) * 4;
    // B staging: wave w handles k-slot 8w..8w+7, lane = local n (0..63)
    const int kloc = wave * 8;
    const int bnl  = lane;

    floatx4 acc0 = {0.f, 0.f, 0.f, 0.f};
    floatx4 acc1 = {0.f, 0.f, 0.f, 0.f};

    for (int k0 = 0; k0 < K; k0 += 32) {
        // ---- stage A tile (f16 already) ----
        *reinterpret_cast<uint2*>(&As[ar][ak]) =
            *reinterpret_cast<const uint2*>(A + (size_t)(bm + ar) * lda + k0 + ak);

        // ---- stage B tile: 8 coalesced fp32 loads down k, cvt, b128 write ----
        float fv[8];
        if (BMODE == 0) {
            int kk = k0 + kloc;
            const float* base = (kk < 2048) ? (Bp0 + (size_t)kk * ldb)
                                            : (Bp1 + (size_t)(kk - 2048) * ldb);
            base += bn + bnl;
#pragma unroll
            for (int j = 0; j < 8; ++j) fv[j] = base[(size_t)j * ldb];
        } else if (BMODE == 1) {
            const float* base = Bp0 + (size_t)(k0 + kloc) * ldb + bn + bnl;
#pragma unroll
            for (int j = 0; j < 8; ++j) fv[j] = base[(size_t)j * ldb];
        } else {
            int third = bn >> 11;
            const float* Bsel = (third == 0) ? Bp0 : ((third == 1) ? Bp1 : Bp2);
            const float* base = Bsel + (size_t)(k0 + kloc) * ldb + (bn - (third << 11)) + bnl;
#pragma unroll
            for (int j = 0; j < 8; ++j) fv[j] = base[(size_t)j * ldb];
        }
        union { unsigned short us[8]; uint4 v; } pk;
#pragma unroll
        for (int j = 0; j < 8; ++j) pk.us[j] = f2h_bits(fv[j]);
        *reinterpret_cast<uint4*>(&Bs[bnl][kloc]) = pk.v;

        __syncthreads();

        // ---- fragments + MFMA ----
        halfx8 afr = *reinterpret_cast<const halfx8*>(&As[wm + fl][qd * 8]);
        halfx8 bf0 = *reinterpret_cast<const halfx8*>(&Bs[wn + fl][qd * 8]);
        halfx8 bf1 = *reinterpret_cast<const halfx8*>(&Bs[wn + 16 + fl][qd * 8]);
        acc0 = __builtin_amdgcn_mfma_f32_16x16x32_f16(afr, bf0, acc0, 0, 0, 0);
        acc1 = __builtin_amdgcn_mfma_f32_16x16x32_f16(afr, bf1, acc1, 0, 0, 0);

        __syncthreads();
    }

    // ---- epilogue. C/D: col = lane&15, row = (lane>>4)*4 + reg ----
    const int row0 = bm + wm + qd * 4;
#pragma unroll
    for (int fn = 0; fn < 2; ++fn) {
        floatx4 a = (fn == 0) ? acc0 : acc1;
        int col = bn + wn + fn * 16 + fl;
#pragma unroll
        for (int rr = 0; rr < 4; ++rr) {
            int row = row0 + rr;
            float v = a[rr];
            if (EPI == 0) {
                int sidx = (row < 64) ? sF : sB;
                v += biasp[col] + ts[2 * sidx] * Wtn[col] + ts[2 * sidx + 1] * Wtn[HH + col];
                v = fmaxf(v, 0.f);
                ((unsigned short*)Cout)[(size_t)row * ldc + col] = f2h_bits(v);
            } else if (EPI == 1) {
                v = fmaxf(v + biasp[col], 0.f);
                ((unsigned short*)Cout)[(size_t)row * ldc + col] = f2h_bits(v);
            } else {
                ((float*)Cout)[(size_t)row * ldc + col] = v;
            }
        }
    }
}

// ---------------------------------------------------------------------------
// block reduce + one atomic per block
// ---------------------------------------------------------------------------
__device__ __forceinline__ void block_reduce_atomic(float v, float* dst) {
    for (int off = 32; off; off >>= 1) v += __shfl_down(v, off, 64);
    __shared__ float red[4];
    if ((threadIdx.x & 63) == 0) red[threadIdx.x >> 6] = v;
    __syncthreads();
    if (threadIdx.x == 0) atomicAdd(dst, red[0] + red[1] + red[2] + red[3]);
}

// ---------------------------------------------------------------------------
// state updates (fp32). STQ holds raw logits; biases/tanh/exp applied here.
// grid: (DD/256, BBr)
// ---------------------------------------------------------------------------
__global__ void update_mom_kernel(const float* __restrict__ pos, float* __restrict__ mom,
                                  float* __restrict__ sld, const float* __restrict__ STQ,
                                  const float* __restrict__ bs, const float* __restrict__ cs,
                                  const float* __restrict__ btr, const float* __restrict__ bq,
                                  const float* __restrict__ cq, const float* __restrict__ eps) {
    int r = blockIdx.y;
    int d = blockIdx.x * 256 + threadIdx.x;
    float e = eps[0];
    size_t ro = (size_t)r * 6144;
    float S = tanhf(STQ[ro + d] + bs[d]) * expf(cs[d]);
    float T = STQ[ro + 2048 + d] + btr[d];
    float Q = tanhf(STQ[ro + 4096 + d] + bq[d]) * expf(cq[d]);
    size_t idx = (size_t)r * 2048 + d;
    float p = pos[idx], v = mom[idx];
    float g = sinf(p);
    float tr = e * Q, sc;
    if (r < 64) { sc = 0.5f * e * S;  v = v * expf(sc) - 0.5f * e * (expf(tr) * g - T); }
    else        { sc = -0.5f * e * S; v = expf(sc) * (v + 0.5f * e * (expf(tr) * g - T)); }
    mom[idx] = v;
    block_reduce_atomic(sc, sld + r);
}

__global__ void update_pos_kernel(float* __restrict__ pos, const float* __restrict__ mom,
                                  float* __restrict__ sld, const float* __restrict__ STQ,
                                  const float* __restrict__ bs, const float* __restrict__ cs,
                                  const float* __restrict__ btr, const float* __restrict__ bq,
                                  const float* __restrict__ cq, const float* __restrict__ eps,
                                  const float* __restrict__ masks, int sF, int sB, int sub) {
    int r = blockIdx.y;
    int d = blockIdx.x * 256 + threadIdx.x;
    float e = eps[0];
    size_t ro = (size_t)r * 6144;
    float S = tanhf(STQ[ro + d] + bs[d]) * expf(cs[d]);
    float T = STQ[ro + 2048 + d] + btr[d];
    float Q = tanhf(STQ[ro + 4096 + d] + bq[d]) * expf(cq[d]);
    size_t idx = (size_t)r * 2048 + d;
    float p = pos[idx], v = mom[idx];
    float sc = e * S, tr = e * Q;
    float pn, ld;
    if (r < 64) {
        float mf = masks[sF * 2048 + d];
        float m  = (sub == 2) ? mf : 1.f - mf;
        float mi = 1.f - m;
        pn = m * p + mi * (p * expf(sc) + e * (expf(tr) * v + T));
        ld = mi * sc;
    } else {
        float mb = masks[sB * 2048 + d];
        float m  = (sub == 2) ? 1.f - mb : mb;
        float mi = 1.f - m;
        pn = m * p + mi * expf(sc) * (p - e * (expf(tr) * v + T));
        ld = mi * sc;
    }
    pos[idx] = pn;
    block_reduce_atomic(ld, sld + r);
}

// ---------------------------------------------------------------------------
// accept prob per row (128 blocks): d = H(pos0,mom0) - H(pos1,mom1) + sld
// ---------------------------------------------------------------------------
__global__ void accept_kernel(const float* __restrict__ position,
                              const float* __restrict__ momf, const float* __restrict__ momb,
                              const float* __restrict__ pos, const float* __restrict__ mom,
                              const float* __restrict__ sld, float* __restrict__ ap_all) {
    int r = blockIdx.x;
    int rb = r & 63;
    const float* m0 = (r < 64) ? (momf + (size_t)rb * 2048) : (momb + (size_t)rb * 2048);
    float s = 0.f;
    for (int d = threadIdx.x; d < 2048; d += 256) {
        float x0 = position[rb * 2048 + d];
        float v0 = m0[d];
        float x1 = pos[(size_t)r * 2048 + d];
        float v1 = mom[(size_t)r * 2048 + d];
        s += (cosf(x1) - cosf(x0)) + 0.5f * (v0 * v0 - v1 * v1);
    }
    for (int off = 32; off; off >>= 1) s += __shfl_down(s, off, 64);
    __shared__ float red[4];
    if ((threadIdx.x & 63) == 0) red[threadIdx.x >> 6] = s;
    __syncthreads();
    if (threadIdx.x == 0) {
        float dd = red[0] + red[1] + red[2] + red[3] + sld[r];
        float p = isnan(dd) ? 0.f : expf(dd < 0.f ? dd : 0.f);
        if (!isfinite(p)) p = 0.f;
        ap_all[r] = p;
    }
}

// ---------------------------------------------------------------------------
// combine -> outputs: [position_post | momentum_post | ap | position_out]
// ---------------------------------------------------------------------------
__global__ void combine_kernel(const float* __restrict__ position,
                               const float* __restrict__ u_dir, const float* __restrict__ u_accept,
                               const float* __restrict__ pos, const float* __restrict__ mom,
                               const float* __restrict__ ap_all, float* __restrict__ out) {
    int idx = blockIdx.x * 256 + threadIdx.x;  // over BD*DD
    int b = idx >> 11, d = idx & 2047;
    float fm = (u_dir[b] > 0.5f) ? 1.f : 0.f;
    float pf = pos[(size_t)b * 2048 + d],       pb = pos[(size_t)(64 + b) * 2048 + d];
    float mf = mom[(size_t)b * 2048 + d],       mb = mom[(size_t)(64 + b) * 2048 + d];
    float ppost = fm * pf + (1.f - fm) * pb;
    float mpost = fm * mf + (1.f - fm) * mb;
    float ap = fm * ap_all[b] + (1.f - fm) * ap_all[64 + b];
    float am = (ap > u_accept[b]) ? 1.f : 0.f;
    out[idx] = ppost;
    out[131072 + idx] = mpost;
    if (d == 0) out[262144 + b] = ap;
    out[262208 + idx] = am * ppost + (1.f - am) * position[idx];
}

// ---------------------------------------------------------------------------
extern "C" void kernel_launch(void* const* d_in, const int* in_sizes, int n_in,
                              void* d_out, int out_size, void* d_ws, size_t ws_size,
                              hipStream_t stream) {
    const float* position   = (const float*)d_in[0];
    const float* momentum_f = (const float*)d_in[1];
    const float* momentum_b = (const float*)d_in[2];
    const float* u_dir      = (const float*)d_in[3];
    const float* u_accept   = (const float*)d_in[4];
    const float* eps        = (const float*)d_in[5];
    const float* masks      = (const float*)d_in[6];
    const float* ts         = (const float*)d_in[7];
    const float* W1         = (const float*)d_in[8];
    const float* W2         = (const float*)d_in[9];
    const float* Wt         = (const float*)d_in[10];
    const float* b1         = (const float*)d_in[11];
    const float* Wh         = (const float*)d_in[12];
    const float* bh         = (const float*)d_in[13];
    const float* Ws         = (const float*)d_in[14];
    const float* bs         = (const float*)d_in[15];
    const float* cs         = (const float*)d_in[16];
    const float* Wtr        = (const float*)d_in[17];
    const float* btr        = (const float*)d_in[18];
    const float* Wq         = (const float*)d_in[19];
    const float* bq         = (const float*)d_in[20];
    const float* cq         = (const float*)d_in[21];
    float* out = (float*)d_out;

    // workspace carve (~8.4 MB)
    float* pos    = (float*)d_ws;               // 128*2048
    float* mom    = pos + BBr * DD;             // 128*2048
    float* sld    = mom + BBr * DD;             // 128
    float* ap_all = sld + BBr;                  // 128
    float* STQ    = ap_all + BBr;               // 128*6144
    unsigned short* Abuf = (unsigned short*)(STQ + BBr * 3 * DD);  // 128*4096 f16
    unsigned short* h1   = Abuf + BBr * 2 * DD;
    unsigned short* h2   = h1 + BBr * HH;

    const size_t DH  = (size_t)DD * HH;
    const size_t HH2 = (size_t)HH * HH;

    init_kernel<<<BBr * DD / 256, 256, 0, stream>>>(position, momentum_f, momentum_b,
                                                    pos, mom, sld);

    for (int i = 0; i < NSS; ++i) {
        int sF = i, sB = NSS - 1 - i;
        for (int subidx = 0; subidx < 4; ++subidx) {
            bool isMom = (subidx == 0 || subidx == 3);
            int n = isMom ? 1 : 0;            // MOM net = 1, POS net = 0
            int sub = (subidx == 1) ? 2 : 3;  // pos sub-update flavor

            if (isMom)
                prep_mom_kernel<<<BBr * DD / 256, 256, 0, stream>>>(pos, Abuf);
            else
                prep_pos_kernel<<<BBr * DD / 256, 256, 0, stream>>>(pos, mom, masks,
                                                                    sF, sB, sub, Abuf);

            gemm_kernel<0, 0><<<dim3(HH / 64, 4), 256, 0, stream>>>(
                Abuf, 2 * DD, 2 * DD,
                W1 + n * DH, W2 + n * DH, nullptr, HH,
                h1, HH,
                b1 + n * HH, Wt + n * 2 * HH, ts, sF, sB);

            gemm_kernel<1, 1><<<dim3(HH / 64, 4), 256, 0, stream>>>(
                h1, HH, HH,
                Wh + n * HH2, nullptr, nullptr, HH,
                h2, HH,
                bh + n * HH, nullptr, ts, sF, sB);

            gemm_kernel<2, 2><<<dim3(3 * DD / 64, 4), 256, 0, stream>>>(
                h2, HH, HH,
                Ws + n * DH, Wtr + n * DH, Wq + n * DH, DD,
                STQ, 3 * DD,
                nullptr, nullptr, ts, sF, sB);

            if (isMom)
                update_mom_kernel<<<dim3(DD / 256, BBr), 256, 0, stream>>>(
                    pos, mom, sld, STQ, bs + DD, cs + DD, btr + DD, bq + DD, cq + DD, eps);
            else
                update_pos_kernel<<<dim3(DD / 256, BBr), 256, 0, stream>>>(
                    pos, mom, sld, STQ, bs, cs, btr, bq, cq, eps, masks, sF, sB, sub);
        }
    }

    accept_kernel<<<BBr, 256, 0, stream>>>(position, momentum_f, momentum_b,
                                           pos, mom, sld, ap_all);
    combine_kernel<<<BD * DD / 256, 256, 0, stream>>>(position, u_dir, u_accept,
                                                      pos, mom, ap_all, out);
}

// Round 2
// 19958.479 us; speedup vs baseline: 1.3105x; 1.3105x over previous
//
#include <hip/hip_runtime.h>

// Problem constants
#define BD   64      // batch per direction
#define DD   2048
#define HH   4096
#define NSS  25
#define BBr  128     // combined rows (fwd 0..63, bwd 64..127)

typedef _Float16 halfx8 __attribute__((ext_vector_type(8)));
typedef float    floatx4 __attribute__((ext_vector_type(4)));

__device__ __forceinline__ unsigned short f2h_bits(float x) {
    union { _Float16 h; unsigned short u; } c;
    c.h = (_Float16)x;
    return c.u;
}

// ---------------------------------------------------------------------------
// init: state + first A-operand (mom-type: [pos | sin(pos)])
// ---------------------------------------------------------------------------
__global__ void init_kernel(const float* __restrict__ position,
                            const float* __restrict__ momf,
                            const float* __restrict__ momb,
                            float* __restrict__ pos, float* __restrict__ mom,
                            float* __restrict__ sld,
                            unsigned short* __restrict__ Abuf) {
    int idx = blockIdx.x * 256 + threadIdx.x;   // over BBr*DD
    int r = idx >> 11, d = idx & 2047;
    float p = position[((r & 63) << 11) + d];
    pos[idx] = p;
    mom[idx] = (r < 64) ? momf[(r << 11) + d] : momb[((r - 64) << 11) + d];
    Abuf[(r << 12) + d]        = f2h_bits(p);
    Abuf[(r << 12) + 2048 + d] = f2h_bits(sinf(p));
    if (idx < BBr) sld[idx] = 0.f;
}

// ---------------------------------------------------------------------------
// Weight conversion: fp32 (rows x cols, ldi) -> f16 transposed (cols x rows, ldo)
// 32x32 LDS tile. grid: (cols/32, rows/32), 256 threads.
// ---------------------------------------------------------------------------
__global__ __launch_bounds__(256) void transpose_cvt_kernel(
        const float* __restrict__ src, int ldi,
        unsigned short* __restrict__ dst, int ldo) {
    __shared__ float tile[32][33];
    const int rb = blockIdx.y * 32;   // src row base
    const int cb = blockIdx.x * 32;   // src col base
    const int t  = threadIdx.x;
    const int r  = t >> 3;
    const int c4 = (t & 7) * 4;
    float4 v = *reinterpret_cast<const float4*>(src + (size_t)(rb + r) * ldi + cb + c4);
    tile[r][c4 + 0] = v.x; tile[r][c4 + 1] = v.y;
    tile[r][c4 + 2] = v.z; tile[r][c4 + 3] = v.w;
    __syncthreads();
    union { unsigned short us[4]; uint2 v; } pk;
#pragma unroll
    for (int j = 0; j < 4; ++j) pk.us[j] = f2h_bits(tile[c4 + j][r]);
    *reinterpret_cast<uint2*>(dst + (size_t)(cb + r) * ldo + rb + c4) = pk.v;
}

// ---------------------------------------------------------------------------
// Fast GEMM: C(128 x N) = A(128 x K, f16 row-major) @ BT(N x K, f16)^T
// No LDS, no barriers: each lane loads A/B fragments directly (16B dwordx4).
// Block: 256 thr = 4 waves; wave w covers rows [32w,32w+32), block covers 16 cols.
// grid.x = N/16.
// EPI 0: relu(+b1 + t@Wt) -> f16 ; EPI 1: relu(+bh) -> f16 ; EPI 2: raw fp32
// ---------------------------------------------------------------------------
template <int EPI>
__global__ __launch_bounds__(256) void gemm_bt_kernel(
        const unsigned short* __restrict__ A, int lda, int K,
        const unsigned short* __restrict__ BT,
        void* __restrict__ Cout, int ldc,
        const float* __restrict__ biasp, const float* __restrict__ Wtn,
        const float* __restrict__ ts, int sF, int sB) {
    const int lane = threadIdx.x & 63;
    const int wave = threadIdx.x >> 6;
    const int fl   = lane & 15;
    const int qd   = lane >> 4;
    const int bn   = blockIdx.x * 16;

    const unsigned short* pa0 = A  + (size_t)(wave * 32 + fl) * lda + qd * 8;
    const unsigned short* pa1 = pa0 + (size_t)16 * lda;
    const unsigned short* pb  = BT + (size_t)(bn + fl) * K + qd * 8;

    floatx4 acc0 = {0.f, 0.f, 0.f, 0.f};
    floatx4 acc1 = {0.f, 0.f, 0.f, 0.f};

    for (int k0 = 0; k0 < K; k0 += 128) {
#pragma unroll
        for (int u = 0; u < 4; ++u) {
            halfx8 a0 = *reinterpret_cast<const halfx8*>(pa0 + u * 32);
            halfx8 a1 = *reinterpret_cast<const halfx8*>(pa1 + u * 32);
            halfx8 b  = *reinterpret_cast<const halfx8*>(pb  + u * 32);
            acc0 = __builtin_amdgcn_mfma_f32_16x16x32_f16(a0, b, acc0, 0, 0, 0);
            acc1 = __builtin_amdgcn_mfma_f32_16x16x32_f16(a1, b, acc1, 0, 0, 0);
        }
        pa0 += 128; pa1 += 128; pb += 128;
    }

    // epilogue: C/D layout col = lane&15, row = (lane>>4)*4 + reg
    const int col = bn + fl;
#pragma unroll
    for (int fn = 0; fn < 2; ++fn) {
        floatx4 a = (fn == 0) ? acc0 : acc1;
        const int row_base = wave * 32 + fn * 16 + qd * 4;
#pragma unroll
        for (int rr = 0; rr < 4; ++rr) {
            int row = row_base + rr;
            float v = a[rr];
            if (EPI == 0) {
                int sidx = (row < 64) ? sF : sB;
                v += biasp[col] + ts[2 * sidx] * Wtn[col] + ts[2 * sidx + 1] * Wtn[HH + col];
                v = fmaxf(v, 0.f);
                ((unsigned short*)Cout)[(size_t)row * ldc + col] = f2h_bits(v);
            } else if (EPI == 1) {
                v = fmaxf(v + biasp[col], 0.f);
                ((unsigned short*)Cout)[(size_t)row * ldc + col] = f2h_bits(v);
            } else {
                ((float*)Cout)[(size_t)row * ldc + col] = v;
            }
        }
    }
}

// ---------------------------------------------------------------------------
// Fallback GEMM (round-1 path, reads fp32 weights directly). BM=32,BN=64,BK=32.
// ---------------------------------------------------------------------------
template <int BMODE, int EPI>
__global__ __launch_bounds__(256) void gemm_kernel(
        const unsigned short* __restrict__ A, int lda, int K,
        const float* __restrict__ Bp0, const float* __restrict__ Bp1,
        const float* __restrict__ Bp2, int ldb,
        void* __restrict__ Cout, int ldc,
        const float* __restrict__ biasp, const float* __restrict__ Wtn,
        const float* __restrict__ ts, int sF, int sB) {
    __shared__ unsigned short As[32][40];
    __shared__ unsigned short Bs[64][40];

    const int tid  = threadIdx.x;
    const int wave = tid >> 6;
    const int lane = tid & 63;
    const int fl   = lane & 15;
    const int qd   = lane >> 4;
    const int bm   = blockIdx.y * 32;
    const int bn   = blockIdx.x * 64;
    const int wm   = (wave >> 1) * 16;
    const int wn   = (wave & 1) * 32;

    const int ar = tid >> 3;
    const int ak = (tid & 7) * 4;
    const int kloc = wave * 8;
    const int bnl  = lane;

    floatx4 acc0 = {0.f, 0.f, 0.f, 0.f};
    floatx4 acc1 = {0.f, 0.f, 0.f, 0.f};

    for (int k0 = 0; k0 < K; k0 += 32) {
        *reinterpret_cast<uint2*>(&As[ar][ak]) =
            *reinterpret_cast<const uint2*>(A + (size_t)(bm + ar) * lda + k0 + ak);

        float fv[8];
        if (BMODE == 0) {
            int kk = k0 + kloc;
            const float* base = (kk < 2048) ? (Bp0 + (size_t)kk * ldb)
                                            : (Bp1 + (size_t)(kk - 2048) * ldb);
            base += bn + bnl;
#pragma unroll
            for (int j = 0; j < 8; ++j) fv[j] = base[(size_t)j * ldb];
        } else if (BMODE == 1) {
            const float* base = Bp0 + (size_t)(k0 + kloc) * ldb + bn + bnl;
#pragma unroll
            for (int j = 0; j < 8; ++j) fv[j] = base[(size_t)j * ldb];
        } else {
            int third = bn >> 11;
            const float* Bsel = (third == 0) ? Bp0 : ((third == 1) ? Bp1 : Bp2);
            const float* base = Bsel + (size_t)(k0 + kloc) * ldb + (bn - (third << 11)) + bnl;
#pragma unroll
            for (int j = 0; j < 8; ++j) fv[j] = base[(size_t)j * ldb];
        }
        union { unsigned short us[8]; uint4 v; } pk;
#pragma unroll
        for (int j = 0; j < 8; ++j) pk.us[j] = f2h_bits(fv[j]);
        *reinterpret_cast<uint4*>(&Bs[bnl][kloc]) = pk.v;

        __syncthreads();

        halfx8 afr = *reinterpret_cast<const halfx8*>(&As[wm + fl][qd * 8]);
        halfx8 bf0 = *reinterpret_cast<const halfx8*>(&Bs[wn + fl][qd * 8]);
        halfx8 bf1 = *reinterpret_cast<const halfx8*>(&Bs[wn + 16 + fl][qd * 8]);
        acc0 = __builtin_amdgcn_mfma_f32_16x16x32_f16(afr, bf0, acc0, 0, 0, 0);
        acc1 = __builtin_amdgcn_mfma_f32_16x16x32_f16(afr, bf1, acc1, 0, 0, 0);

        __syncthreads();
    }

    const int row0 = bm + wm + qd * 4;
#pragma unroll
    for (int fn = 0; fn < 2; ++fn) {
        floatx4 a = (fn == 0) ? acc0 : acc1;
        int col = bn + wn + fn * 16 + fl;
#pragma unroll
        for (int rr = 0; rr < 4; ++rr) {
            int row = row0 + rr;
            float v = a[rr];
            if (EPI == 0) {
                int sidx = (row < 64) ? sF : sB;
                v += biasp[col] + ts[2 * sidx] * Wtn[col] + ts[2 * sidx + 1] * Wtn[HH + col];
                v = fmaxf(v, 0.f);
                ((unsigned short*)Cout)[(size_t)row * ldc + col] = f2h_bits(v);
            } else if (EPI == 1) {
                v = fmaxf(v + biasp[col], 0.f);
                ((unsigned short*)Cout)[(size_t)row * ldc + col] = f2h_bits(v);
            } else {
                ((float*)Cout)[(size_t)row * ldc + col] = v;
            }
        }
    }
}

// ---------------------------------------------------------------------------
// block reduce + one atomic per block
// ---------------------------------------------------------------------------
__device__ __forceinline__ void block_reduce_atomic(float v, float* dst) {
    for (int off = 32; off; off >>= 1) v += __shfl_down(v, off, 64);
    __shared__ float red[4];
    if ((threadIdx.x & 63) == 0) red[threadIdx.x >> 6] = v;
    __syncthreads();
    if (threadIdx.x == 0) atomicAdd(dst, red[0] + red[1] + red[2] + red[3]);
}

// ---------------------------------------------------------------------------
// fused update kernels: apply state update AND write next sub-step's A-operand
// grid: (DD/256, BBr)
// ---------------------------------------------------------------------------
__global__ void update_mom_kernel(const float* __restrict__ pos, float* __restrict__ mom,
                                  float* __restrict__ sld, const float* __restrict__ STQ,
                                  const float* __restrict__ bs, const float* __restrict__ cs,
                                  const float* __restrict__ btr, const float* __restrict__ bq,
                                  const float* __restrict__ cq, const float* __restrict__ eps,
                                  const float* __restrict__ masks, int sF, int sB,
                                  int writeNext, unsigned short* __restrict__ Abuf) {
    int r = blockIdx.y;
    int d = blockIdx.x * 256 + threadIdx.x;
    float e = eps[0];
    size_t ro = (size_t)r * 6144;
    float S = tanhf(STQ[ro + d] + bs[d]) * expf(cs[d]);
    float T = STQ[ro + 2048 + d] + btr[d];
    float Q = tanhf(STQ[ro + 4096 + d] + bq[d]) * expf(cq[d]);
    size_t idx = (size_t)r * 2048 + d;
    float p = pos[idx], v = mom[idx];
    float g = sinf(p);
    float tr = e * Q, sc;
    if (r < 64) { sc = 0.5f * e * S;  v = v * expf(sc) - 0.5f * e * (expf(tr) * g - T); }
    else        { sc = -0.5f * e * S; v = expf(sc) * (v + 0.5f * e * (expf(tr) * g - T)); }
    mom[idx] = v;
    if (writeNext) {   // next sub is pos-type with sub==2
        float m2 = (r < 64) ? masks[sF * 2048 + d] : 1.f - masks[sB * 2048 + d];
        Abuf[(r << 12) + d]        = f2h_bits(v);
        Abuf[(r << 12) + 2048 + d] = f2h_bits(m2 * p);
    }
    block_reduce_atomic(sc, sld + r);
}

__global__ void update_pos_kernel(float* __restrict__ pos, const float* __restrict__ mom,
                                  float* __restrict__ sld, const float* __restrict__ STQ,
                                  const float* __restrict__ bs, const float* __restrict__ cs,
                                  const float* __restrict__ btr, const float* __restrict__ bq,
                                  const float* __restrict__ cq, const float* __restrict__ eps,
                                  const float* __restrict__ masks, int sF, int sB, int sub,
                                  unsigned short* __restrict__ Abuf) {
    int r = blockIdx.y;
    int d = blockIdx.x * 256 + threadIdx.x;
    float e = eps[0];
    size_t ro = (size_t)r * 6144;
    float S = tanhf(STQ[ro + d] + bs[d]) * expf(cs[d]);
    float T = STQ[ro + 2048 + d] + btr[d];
    float Q = tanhf(STQ[ro + 4096 + d] + bq[d]) * expf(cq[d]);
    size_t idx = (size_t)r * 2048 + d;
    float p = pos[idx], v = mom[idx];
    float sc = e * S, tr = e * Q;
    float mf = masks[sF * 2048 + d], mb = masks[sB * 2048 + d];
    float pn, ld;
    if (r < 64) {
        float m  = (sub == 2) ? mf : 1.f - mf;
        float mi = 1.f - m;
        pn = m * p + mi * (p * expf(sc) + e * (expf(tr) * v + T));
        ld = mi * sc;
    } else {
        float m  = (sub == 2) ? 1.f - mb : mb;
        float mi = 1.f - m;
        pn = m * p + mi * expf(sc) * (p - e * (expf(tr) * v + T));
        ld = mi * sc;
    }
    pos[idx] = pn;
    if (sub == 2) {   // next sub is pos-type with sub==3
        float m3 = (r < 64) ? 1.f - mf : mb;
        Abuf[(r << 12) + d]        = f2h_bits(v);
        Abuf[(r << 12) + 2048 + d] = f2h_bits(m3 * pn);
    } else {          // next sub is mom-type
        Abuf[(r << 12) + d]        = f2h_bits(pn);
        Abuf[(r << 12) + 2048 + d] = f2h_bits(sinf(pn));
    }
    block_reduce_atomic(ld, sld + r);
}

// ---------------------------------------------------------------------------
// accept prob per row (128 blocks)
// ---------------------------------------------------------------------------
__global__ void accept_kernel(const float* __restrict__ position,
                              const float* __restrict__ momf, const float* __restrict__ momb,
                              const float* __restrict__ pos, const float* __restrict__ mom,
                              const float* __restrict__ sld, float* __restrict__ ap_all) {
    int r = blockIdx.x;
    int rb = r & 63;
    const float* m0 = (r < 64) ? (momf + (size_t)rb * 2048) : (momb + (size_t)rb * 2048);
    float s = 0.f;
    for (int d = threadIdx.x; d < 2048; d += 256) {
        float x0 = position[rb * 2048 + d];
        float v0 = m0[d];
        float x1 = pos[(size_t)r * 2048 + d];
        float v1 = mom[(size_t)r * 2048 + d];
        s += (cosf(x1) - cosf(x0)) + 0.5f * (v0 * v0 - v1 * v1);
    }
    for (int off = 32; off; off >>= 1) s += __shfl_down(s, off, 64);
    __shared__ float red[4];
    if ((threadIdx.x & 63) == 0) red[threadIdx.x >> 6] = s;
    __syncthreads();
    if (threadIdx.x == 0) {
        float dd = red[0] + red[1] + red[2] + red[3] + sld[r];
        float p = isnan(dd) ? 0.f : expf(dd < 0.f ? dd : 0.f);
        if (!isfinite(p)) p = 0.f;
        ap_all[r] = p;
    }
}

// ---------------------------------------------------------------------------
// combine -> outputs: [position_post | momentum_post | ap | position_out]
// ---------------------------------------------------------------------------
__global__ void combine_kernel(const float* __restrict__ position,
                               const float* __restrict__ u_dir, const float* __restrict__ u_accept,
                               const float* __restrict__ pos, const float* __restrict__ mom,
                               const float* __restrict__ ap_all, float* __restrict__ out) {
    int idx = blockIdx.x * 256 + threadIdx.x;  // over BD*DD
    int b = idx >> 11, d = idx & 2047;
    float fm = (u_dir[b] > 0.5f) ? 1.f : 0.f;
    float pf = pos[(size_t)b * 2048 + d],       pb = pos[(size_t)(64 + b) * 2048 + d];
    float mf = mom[(size_t)b * 2048 + d],       mb = mom[(size_t)(64 + b) * 2048 + d];
    float ppost = fm * pf + (1.f - fm) * pb;
    float mpost = fm * mf + (1.f - fm) * mb;
    float ap = fm * ap_all[b] + (1.f - fm) * ap_all[64 + b];
    float am = (ap > u_accept[b]) ? 1.f : 0.f;
    out[idx] = ppost;
    out[131072 + idx] = mpost;
    if (d == 0) out[262144 + b] = ap;
    out[262208 + idx] = am * ppost + (1.f - am) * position[idx];
}

// ---------------------------------------------------------------------------
extern "C" void kernel_launch(void* const* d_in, const int* in_sizes, int n_in,
                              void* d_out, int out_size, void* d_ws, size_t ws_size,
                              hipStream_t stream) {
    const float* position   = (const float*)d_in[0];
    const float* momentum_f = (const float*)d_in[1];
    const float* momentum_b = (const float*)d_in[2];
    const float* u_dir      = (const float*)d_in[3];
    const float* u_accept   = (const float*)d_in[4];
    const float* eps        = (const float*)d_in[5];
    const float* masks      = (const float*)d_in[6];
    const float* ts         = (const float*)d_in[7];
    const float* W1         = (const float*)d_in[8];
    const float* W2         = (const float*)d_in[9];
    const float* Wt         = (const float*)d_in[10];
    const float* b1         = (const float*)d_in[11];
    const float* Wh         = (const float*)d_in[12];
    const float* bh         = (const float*)d_in[13];
    const float* Ws         = (const float*)d_in[14];
    const float* bs         = (const float*)d_in[15];
    const float* cs         = (const float*)d_in[16];
    const float* Wtr        = (const float*)d_in[17];
    const float* btr        = (const float*)d_in[18];
    const float* Wq         = (const float*)d_in[19];
    const float* bq         = (const float*)d_in[20];
    const float* cq         = (const float*)d_in[21];
    float* out = (float*)d_out;

    // ---- workspace carve ----
    float* pos    = (float*)d_ws;               // 128*2048
    float* mom    = pos + BBr * DD;
    float* sld    = mom + BBr * DD;             // 128
    float* ap_all = sld + BBr;                  // 128
    float* STQ    = ap_all + BBr;               // 128*6144
    unsigned short* Abuf = (unsigned short*)(STQ + BBr * 3 * DD);  // 128*4096
    unsigned short* h1   = Abuf + (size_t)BBr * 2 * DD;            // 128*4096
    unsigned short* h2   = h1 + (size_t)BBr * HH;                  // 128*4096
    unsigned short* BTw  = h2 + (size_t)BBr * HH;                  // weights f16

    const size_t BT1sz = (size_t)HH * 2 * DD;   // 4096*4096
    const size_t BThsz = (size_t)HH * HH;       // 4096*4096
    const size_t BT3sz = (size_t)3 * DD * HH;   // 6144*4096
    const size_t perNet = BT1sz + BThsz + BT3sz;
    unsigned short* BT1[2] = { BTw,                 BTw + perNet };
    unsigned short* BTh[2] = { BTw + BT1sz,         BTw + perNet + BT1sz };
    unsigned short* BT3[2] = { BTw + BT1sz + BThsz, BTw + perNet + BT1sz + BThsz };

    const size_t NEED = (size_t)((char*)(BTw + 2 * perNet) - (char*)d_ws);
    const bool fast = (ws_size >= NEED);

    const size_t DH  = (size_t)DD * HH;
    const size_t HH2 = (size_t)HH * HH;

    init_kernel<<<BBr * DD / 256, 256, 0, stream>>>(position, momentum_f, momentum_b,
                                                    pos, mom, sld, Abuf);

    if (fast) {
        // weight conversion: fp32 KxN -> f16 NxK (transposed)
        for (int n = 0; n < 2; ++n) {
            // GEMM1: rows n (H), cols k = [W1 | W2]
            transpose_cvt_kernel<<<dim3(HH / 32, DD / 32), 256, 0, stream>>>(
                W1 + n * DH, HH, BT1[n], 2 * DD);
            transpose_cvt_kernel<<<dim3(HH / 32, DD / 32), 256, 0, stream>>>(
                W2 + n * DH, HH, BT1[n] + DD, 2 * DD);
            // GEMM2: Wh
            transpose_cvt_kernel<<<dim3(HH / 32, HH / 32), 256, 0, stream>>>(
                Wh + n * HH2, HH, BTh[n], HH);
            // GEMM3: rows n = [Ws-d | Wtr-d | Wq-d], cols k (H)
            transpose_cvt_kernel<<<dim3(DD / 32, HH / 32), 256, 0, stream>>>(
                Ws + n * DH, DD, BT3[n], HH);
            transpose_cvt_kernel<<<dim3(DD / 32, HH / 32), 256, 0, stream>>>(
                Wtr + n * DH, DD, BT3[n] + (size_t)DD * HH, HH);
            transpose_cvt_kernel<<<dim3(DD / 32, HH / 32), 256, 0, stream>>>(
                Wq + n * DH, DD, BT3[n] + (size_t)2 * DD * HH, HH);
        }
    }

    for (int i = 0; i < NSS; ++i) {
        int sF = i, sB = NSS - 1 - i;
        for (int subidx = 0; subidx < 4; ++subidx) {
            bool isMom = (subidx == 0 || subidx == 3);
            int n = isMom ? 1 : 0;            // MOM net = 1, POS net = 0
            int sub = (subidx == 1) ? 2 : 3;  // pos sub-update flavor

            if (fast) {
                gemm_bt_kernel<0><<<HH / 16, 256, 0, stream>>>(
                    Abuf, 2 * DD, 2 * DD, BT1[n], h1, HH,
                    b1 + n * HH, Wt + n * 2 * HH, ts, sF, sB);
                gemm_bt_kernel<1><<<HH / 16, 256, 0, stream>>>(
                    h1, HH, HH, BTh[n], h2, HH,
                    bh + n * HH, nullptr, ts, sF, sB);
                gemm_bt_kernel<2><<<3 * DD / 16, 256, 0, stream>>>(
                    h2, HH, HH, BT3[n], STQ, 3 * DD,
                    nullptr, nullptr, ts, sF, sB);
            } else {
                gemm_kernel<0, 0><<<dim3(HH / 64, 4), 256, 0, stream>>>(
                    Abuf, 2 * DD, 2 * DD,
                    W1 + n * DH, W2 + n * DH, nullptr, HH, h1, HH,
                    b1 + n * HH, Wt + n * 2 * HH, ts, sF, sB);
                gemm_kernel<1, 1><<<dim3(HH / 64, 4), 256, 0, stream>>>(
                    h1, HH, HH, Wh + n * HH2, nullptr, nullptr, HH, h2, HH,
                    bh + n * HH, nullptr, ts, sF, sB);
                gemm_kernel<2, 2><<<dim3(3 * DD / 64, 4), 256, 0, stream>>>(
                    h2, HH, HH, Ws + n * DH, Wtr + n * DH, Wq + n * DH, DD, STQ, 3 * DD,
                    nullptr, nullptr, ts, sF, sB);
            }

            if (isMom)
                update_mom_kernel<<<dim3(DD / 256, BBr), 256, 0, stream>>>(
                    pos, mom, sld, STQ, bs + DD, cs + DD, btr + DD, bq + DD, cq + DD,
                    eps, masks, sF, sB, (subidx == 0) ? 1 : 0, Abuf);
            else
                update_pos_kernel<<<dim3(DD / 256, BBr), 256, 0, stream>>>(
                    pos, mom, sld, STQ, bs, cs, btr, bq, cq, eps, masks, sF, sB, sub, Abuf);
        }
    }

    accept_kernel<<<BBr, 256, 0, stream>>>(position, momentum_f, momentum_b,
                                           pos, mom, sld, ap_all);
    combine_kernel<<<BD * DD / 256, 256, 0, stream>>>(position, u_dir, u_accept,
                                                      pos, mom, ap_all, out);
}